// Round 6
// baseline (195.902 us; speedup 1.0000x reference)
//
#include <hip/hip_runtime.h>
#include <hip/hip_bf16.h>
#include <stdint.h>

#define NH 16
#define SEQ 1024
#define EMB 1024
#define HDIM 64
#define BATCH 4
#define SPAD 1032  // strip row length in bf16 (1024 + 8 pad)

typedef float f32x4 __attribute__((ext_vector_type(4)));
typedef short bf16x8 __attribute__((ext_vector_type(8)));

static __device__ __forceinline__ short f2bf(float f) {
  union { float f; uint32_t u; } v; v.f = f;
  uint32_t r = (v.u + 0x7FFF + ((v.u >> 16) & 1)) >> 16;
  return (short)(uint16_t)r;
}
static __device__ __forceinline__ float bf2f(short h) {
  union { uint32_t u; float f; } v; v.u = ((uint32_t)(uint16_t)h) << 16;
  return v.f;
}

static __device__ __forceinline__ void gload_lds16(const void* g, void* l) {
  __builtin_amdgcn_global_load_lds(
      (const __attribute__((address_space(1))) void*)g,
      (__attribute__((address_space(3))) void*)l, 16, 0, 0);
}

// ---------- fp32 -> bf16 convert, 3 buffers fused ----------
static __device__ __forceinline__ void cvt8(const float* s, short* d) {
  const float4* sv = (const float4*)s;
  float4 a = sv[0], b = sv[1];
  bf16x8 o;
  o[0] = f2bf(a.x); o[1] = f2bf(a.y); o[2] = f2bf(a.z); o[3] = f2bf(a.w);
  o[4] = f2bf(b.x); o[5] = f2bf(b.y); o[6] = f2bf(b.z); o[7] = f2bf(b.w);
  *(bf16x8*)d = o;
}

__global__ void cvt3_kernel(const float* __restrict__ x, const float* __restrict__ w,
                            const float* __restrict__ o, short* __restrict__ xb,
                            short* __restrict__ wb, short* __restrict__ ob) {
  int i = (blockIdx.x * blockDim.x + threadIdx.x) * 8;
  if (i < 4194304) {
    cvt8(x + i, xb + i);
  } else if (i < 7340032) {
    cvt8(w + (i - 4194304), wb + (i - 4194304));
  } else {
    cvt8(o + (i - 7340032), ob + (i - 7340032));
  }
}

// ---------- V [bh][s][d] -> V^T [bh][d][s] (bf16, 64x64 LDS tiles) ----------
__global__ __launch_bounds__(256) void transpose_v(const short* __restrict__ v,
                                                   short* __restrict__ vt) {
  __shared__ short t[64][72];
  const int tid = threadIdx.x;
  const int bh = blockIdx.y;
  const int sb = blockIdx.x * 64;
  const int row = tid >> 2;        // 0..63
  const int c0 = (tid & 3) * 16;   // 0,16,32,48
  const short* src = v + ((size_t)(bh * SEQ + sb + row)) * HDIM + c0;
  *(bf16x8*)&t[row][c0] = *(const bf16x8*)src;
  *(bf16x8*)&t[row][c0 + 8] = *(const bf16x8*)(src + 8);
  __syncthreads();
  bf16x8 o0, o1;
#pragma unroll
  for (int i = 0; i < 8; ++i) o0[i] = t[c0 + i][row];
#pragma unroll
  for (int i = 0; i < 8; ++i) o1[i] = t[c0 + 8 + i][row];
  short* dst = vt + ((size_t)(bh * HDIM + row)) * SEQ + sb + c0;
  *(bf16x8*)dst = o0;
  *(bf16x8*)(dst + 8) = o1;
}

// ---------- 128x128x64 NT GEMM, single-buffer, XCD-chunked swizzle ----------
// grid: 768 1D blocks; each XCD owns 3 consecutive col-blocks x 32 row-blocks
// so its B-panel (3 x 256 KB) stays L2-resident.
__global__ __launch_bounds__(256) void gemm_qkv(
    const short* __restrict__ A, const short* __restrict__ Bm,
    const float* __restrict__ bias, short* __restrict__ qkvws) {
  __shared__ short As[128 * 64];
  __shared__ short Bs[128 * 64];
  const int tid = threadIdx.x;
  const int w = tid >> 6, l = tid & 63;
  const int l15 = l & 15, l4 = l >> 4;
  const int wr = w >> 1, wc = w & 1;
  // XCD swizzle: lin -> (xcd = lin&7) gets blocks [xcd*96, xcd*96+96)
  const int lin = blockIdx.x;
  const int gid = (lin & 7) * 96 + (lin >> 3);
  const int row0 = (gid & 31) * 128;   // bx in [0,32)
  const int col0 = (gid >> 5) * 128;   // by in [0,24)
  const int K = EMB;

  f32x4 acc[4][4] = {};

  const int o = (w * 4) * 1024 + l * 16;
  for (int k0 = 0; k0 < K; k0 += 64) {
#pragma unroll
    for (int c = 0; c < 4; ++c) {
      int oo = o + c * 1024;
      int row = oo >> 7;
      int colb = oo & 127;
      int scol = colb ^ ((row & 7) << 4);  // pre-swizzled source col
      gload_lds16((const char*)A + ((size_t)(row0 + row) * K + k0) * 2 + scol,
                  (char*)As + (w * 4 + c) * 1024);
      gload_lds16((const char*)Bm + ((size_t)(col0 + row) * K + k0) * 2 + scol,
                  (char*)Bs + (w * 4 + c) * 1024);
    }
    __syncthreads();
#pragma unroll
    for (int kk = 0; kk < 2; ++kk) {
      bf16x8 af[4], bfr[4];
      const int kb = (kk * 64 + l4 * 16) ^ ((l15 & 7) << 4);
#pragma unroll
      for (int i = 0; i < 4; ++i) {
        af[i] = *(const bf16x8*)((const char*)As + (wr * 64 + i * 16 + l15) * 128 + kb);
        bfr[i] = *(const bf16x8*)((const char*)Bs + (wc * 64 + i * 16 + l15) * 128 + kb);
      }
#pragma unroll
      for (int i = 0; i < 4; ++i)
#pragma unroll
        for (int j = 0; j < 4; ++j)
          acc[i][j] = __builtin_amdgcn_mfma_f32_16x16x32_bf16(af[i], bfr[j], acc[i][j], 0, 0, 0);
    }
    __syncthreads();
  }

#pragma unroll
  for (int j = 0; j < 4; ++j) {
    int f = col0 + wc * 64 + j * 16 + l15;
    float bv = bias[f];
    int part = f >> 10;               // 0=Q 1=K 2=V
    int e = f & 1023;
    int hh = e >> 6, d = e & 63;
#pragma unroll
    for (int i = 0; i < 4; ++i) {
#pragma unroll
      for (int rr = 0; rr < 4; ++rr) {
        int m = row0 + wr * 64 + i * 16 + l4 * 4 + rr;
        int bb = m >> 10, ss = m & 1023;
        qkvws[(size_t)part * 4194304 +
              ((size_t)(bb * NH + hh) * SEQ + ss) * HDIM + d] =
            f2bf(acc[i][j][rr] + bv);
      }
    }
  }
}

// ---------- 128x64x64 NT GEMM for out-proj, single-buffer, XCD swizzle ----------
__global__ __launch_bounds__(256) void gemm_out64(
    const short* __restrict__ A, const short* __restrict__ Bm,
    const float* __restrict__ bias, float* __restrict__ outp) {
  __shared__ short As[128 * 64];
  __shared__ short Bs[64 * 64];
  const int tid = threadIdx.x;
  const int w = tid >> 6, l = tid & 63;
  const int l15 = l & 15, l4 = l >> 4;
  // 512 blocks; each XCD owns 2 consecutive col-blocks x 32 row-blocks.
  const int lin = blockIdx.x;
  const int gid = (lin & 7) * 64 + (lin >> 3);
  const int row0 = (gid & 31) * 128;
  const int col0 = (gid >> 5) * 64;
  const int K = EMB;

  f32x4 acc[2][4] = {};

  const int oA = (w * 4) * 1024 + l * 16;
  const int oB = (w * 2) * 1024 + l * 16;
  for (int k0 = 0; k0 < K; k0 += 64) {
#pragma unroll
    for (int c = 0; c < 4; ++c) {
      int oo = oA + c * 1024;
      int row = oo >> 7;
      int colb = oo & 127;
      int scol = colb ^ ((row & 7) << 4);
      gload_lds16((const char*)A + ((size_t)(row0 + row) * K + k0) * 2 + scol,
                  (char*)As + (w * 4 + c) * 1024);
    }
#pragma unroll
    for (int c = 0; c < 2; ++c) {
      int oo = oB + c * 1024;
      int row = oo >> 7;
      int colb = oo & 127;
      int scol = colb ^ ((row & 7) << 4);
      gload_lds16((const char*)Bm + ((size_t)(col0 + row) * K + k0) * 2 + scol,
                  (char*)Bs + (w * 2 + c) * 1024);
    }
    __syncthreads();
#pragma unroll
    for (int kk = 0; kk < 2; ++kk) {
      bf16x8 af[2], bfr[4];
      const int kb = (kk * 64 + l4 * 16) ^ ((l15 & 7) << 4);
#pragma unroll
      for (int i = 0; i < 2; ++i)
        af[i] = *(const bf16x8*)((const char*)As + (w * 32 + i * 16 + l15) * 128 + kb);
#pragma unroll
      for (int j = 0; j < 4; ++j)
        bfr[j] = *(const bf16x8*)((const char*)Bs + (j * 16 + l15) * 128 + kb);
#pragma unroll
      for (int i = 0; i < 2; ++i)
#pragma unroll
        for (int j = 0; j < 4; ++j)
          acc[i][j] = __builtin_amdgcn_mfma_f32_16x16x32_bf16(af[i], bfr[j], acc[i][j], 0, 0, 0);
    }
    __syncthreads();
  }

#pragma unroll
  for (int j = 0; j < 4; ++j) {
    int f = col0 + j * 16 + l15;
    float bv = bias[f];
#pragma unroll
    for (int i = 0; i < 2; ++i)
#pragma unroll
      for (int rr = 0; rr < 4; ++rr) {
        int m = row0 + w * 32 + i * 16 + l4 * 4 + rr;
        __builtin_nontemporal_store(acc[i][j][rr] + bv, &outp[(size_t)m * EMB + f]);
      }
  }
}

// ---------- fused attention per (b,h, 16-row block); 4 blocks/CU ----------
__global__ __launch_bounds__(256) void attn_kernel(
    const short* __restrict__ qws, const short* __restrict__ kws,
    const short* __restrict__ vtws, float* __restrict__ attg,
    short* __restrict__ aow) {
  __shared__ short strip[16 * SPAD];  // unnormalized exp(scores), bf16 (33 KB)
  __shared__ float wsum[4][16];
  __shared__ float inv_sum[16];

  const int tid = threadIdx.x;
  const int w = tid >> 6, l = tid & 63;
  const int l15 = l & 15, l4 = l >> 4;
  const int blk = blockIdx.x;
  const int bh = blk >> 6;       // 0..63
  const int r = blk & 63;        // 16-row block index
  const int rowbase = r * 16;

  const short* qb = qws + ((size_t)bh * SEQ + rowbase) * HDIM;
  const short* kb = kws + (size_t)bh * SEQ * HDIM;
  const short* vb = vtws + (size_t)bh * HDIM * SEQ;

  bf16x8 qf[2];
#pragma unroll
  for (int ks = 0; ks < 2; ++ks)
    qf[ks] = *(const bf16x8*)(qb + l15 * HDIM + ks * 32 + l4 * 8);

  const int ng2 = (r + 2) & ~1;
  float psum[4] = {};

  for (int g = w; g < ng2; g += 4) {
    const short* kg = kb + (g * 16 + l15) * HDIM + l4 * 8;
    bf16x8 kf0 = *(const bf16x8*)(kg);
    bf16x8 kf1 = *(const bf16x8*)(kg + 32);
    f32x4 a0 = {};
    a0 = __builtin_amdgcn_mfma_f32_16x16x32_bf16(qf[0], kf0, a0, 0, 0, 0);
    a0 = __builtin_amdgcn_mfma_f32_16x16x32_bf16(qf[1], kf1, a0, 0, 0, 0);
    int col = g * 16 + l15;
#pragma unroll
    for (int rr = 0; rr < 4; ++rr) {
      int rloc = l4 * 4 + rr;
      int row = rowbase + rloc;
      float sv = a0[rr] * 0.125f;
      float ev = (col <= row) ? __expf(sv) : 0.0f;
      psum[rr] += ev;
      strip[rloc * SPAD + col] = f2bf(ev);
    }
  }

#pragma unroll
  for (int rr = 0; rr < 4; ++rr) {
    float v = psum[rr];
    v += __shfl_xor(v, 1);
    v += __shfl_xor(v, 2);
    v += __shfl_xor(v, 4);
    v += __shfl_xor(v, 8);
    psum[rr] = v;
  }
  if (l15 == 0) {
#pragma unroll
    for (int rr = 0; rr < 4; ++rr)
      wsum[w][l4 * 4 + rr] = psum[rr];
  }
  __syncthreads();
  if (tid < 16) {
    float s = wsum[0][tid] + wsum[1][tid] + wsum[2][tid] + wsum[3][tid];
    inv_sum[tid] = 1.0f / s;
  }
  __syncthreads();

  // write normalized att (full 1024 cols; zeros beyond causal limit), NT stores
  {
    const int limit = ng2 * 16;
    const int rloc = tid >> 4;       // 0..15
    const int cb = tid & 15;
    float* arow = attg + (size_t)bh * SEQ * SEQ + (size_t)(rowbase + rloc) * SEQ;
    float isr = inv_sum[rloc];
#pragma unroll
    for (int i = 0; i < 8; ++i) {
      int c = (cb + i * 16) * 8;
      f32x4 o0, o1;
      if (c < limit) {
        bf16x8 p = *(const bf16x8*)&strip[rloc * SPAD + c];
        o0[0] = bf2f(p[0]) * isr; o0[1] = bf2f(p[1]) * isr;
        o0[2] = bf2f(p[2]) * isr; o0[3] = bf2f(p[3]) * isr;
        o1[0] = bf2f(p[4]) * isr; o1[1] = bf2f(p[5]) * isr;
        o1[2] = bf2f(p[6]) * isr; o1[3] = bf2f(p[7]) * isr;
      } else {
        o0 = (f32x4)0.0f;
        o1 = (f32x4)0.0f;
      }
      __builtin_nontemporal_store(o0, (f32x4*)(arow + c));
      __builtin_nontemporal_store(o1, (f32x4*)(arow + c + 4));
    }
  }

  // PV: out[16 x 64] from strip (unnormalized) x V^T, scale rows by inv_sum
  {
    const int nch = ng2 >> 1;
    const int d0 = w * 16;
    f32x4 oacc = {};
    const short* vrow = vb + (d0 + l15) * SEQ + l4 * 8;
    for (int c = 0; c < nch; ++c) {
      bf16x8 vf = *(const bf16x8*)(vrow + c * 32);
      bf16x8 p0 = *(const bf16x8*)&strip[l15 * SPAD + c * 32 + l4 * 8];
      oacc = __builtin_amdgcn_mfma_f32_16x16x32_bf16(p0, vf, oacc, 0, 0, 0);
    }
    const int b = bh >> 4, h = bh & 15;
#pragma unroll
    for (int rr = 0; rr < 4; ++rr) {
      int rloc = l4 * 4 + rr;
      int s = rowbase + rloc;
      float v = oacc[rr] * inv_sum[rloc];
      aow[((size_t)(b * SEQ + s)) * EMB + h * HDIM + d0 + l15] = f2bf(v);
    }
  }
}

extern "C" void kernel_launch(void* const* d_in, const int* in_sizes, int n_in,
                              void* d_out, int out_size, void* d_ws, size_t ws_size,
                              hipStream_t stream) {
  (void)in_sizes; (void)n_in; (void)out_size; (void)ws_size;
  const float* x = (const float*)d_in[0];
  const float* ipw = (const float*)d_in[2];
  const float* ipb = (const float*)d_in[3];
  const float* ow = (const float*)d_in[4];
  const float* ob = (const float*)d_in[5];
  float* outp = (float*)d_out;
  float* attg = (float*)d_out + (size_t)BATCH * SEQ * EMB;

  char* ws = (char*)d_ws;
  short* xbf = (short*)(ws);                   //  8,388,608 B (dead after QKV gemm)
  short* wbf = (short*)(ws + 8388608);         //  6,291,456 B
  short* owbf = (short*)(ws + 14680064);       //  2,097,152 B
  short* qkvws = (short*)(ws + 16777216);      // 25,165,824 B  (Q | K | V, [bh][s][d])
  short* aow = (short*)(ws + 41943040);        //  8,388,608 B -> 50,331,648 total
  short* vtws = (short*)(ws);                  // aliases xbf (dead by transpose time)

  short* qws = qkvws;
  short* kws = qkvws + 4194304;
  short* vws = qkvws + 8388608;

  cvt3_kernel<<<4096, 256, 0, stream>>>(x, ipw, ow, xbf, wbf, owbf);

  gemm_qkv<<<768, 256, 0, stream>>>(xbf, wbf, ipb, qkvws);

  transpose_v<<<dim3(16, 64), 256, 0, stream>>>(vws, vtws);

  attn_kernel<<<4096, 256, 0, stream>>>(qws, kws, vtws, attg, aow);

  gemm_out64<<<512, 256, 0, stream>>>(aow, owbf, ob, outp);
}

// Round 7
// 177.035 us; speedup vs baseline: 1.1066x; 1.1066x over previous
//
#include <hip/hip_runtime.h>
#include <hip/hip_bf16.h>
#include <stdint.h>

#define NH 16
#define SEQ 1024
#define EMB 1024
#define HDIM 64
#define BATCH 4
#define SPAD 1032  // strip row length in bf16 (1024 + 8 pad)

typedef float f32x4 __attribute__((ext_vector_type(4)));
typedef short bf16x8 __attribute__((ext_vector_type(8)));

static __device__ __forceinline__ short f2bf(float f) {
  union { float f; uint32_t u; } v; v.f = f;
  uint32_t r = (v.u + 0x7FFF + ((v.u >> 16) & 1)) >> 16;
  return (short)(uint16_t)r;
}
static __device__ __forceinline__ float bf2f(short h) {
  union { uint32_t u; float f; } v; v.u = ((uint32_t)(uint16_t)h) << 16;
  return v.f;
}

static __device__ __forceinline__ void gload_lds16(const void* g, void* l) {
  __builtin_amdgcn_global_load_lds(
      (const __attribute__((address_space(1))) void*)g,
      (__attribute__((address_space(3))) void*)l, 16, 0, 0);
}

// ---------- fp32 -> bf16 convert, 3 buffers fused ----------
static __device__ __forceinline__ void cvt8(const float* s, short* d) {
  const float4* sv = (const float4*)s;
  float4 a = sv[0], b = sv[1];
  bf16x8 o;
  o[0] = f2bf(a.x); o[1] = f2bf(a.y); o[2] = f2bf(a.z); o[3] = f2bf(a.w);
  o[4] = f2bf(b.x); o[5] = f2bf(b.y); o[6] = f2bf(b.z); o[7] = f2bf(b.w);
  *(bf16x8*)d = o;
}

__global__ void cvt3_kernel(const float* __restrict__ x, const float* __restrict__ w,
                            const float* __restrict__ o, short* __restrict__ xb,
                            short* __restrict__ wb, short* __restrict__ ob) {
  int i = (blockIdx.x * blockDim.x + threadIdx.x) * 8;
  if (i < 4194304) {
    cvt8(x + i, xb + i);
  } else if (i < 7340032) {
    cvt8(w + (i - 4194304), wb + (i - 4194304));
  } else {
    cvt8(o + (i - 7340032), ob + (i - 7340032));
  }
}

// ---------- V [bh][s][d] -> V^T [bh][d][s] (bf16, 64x64 LDS tiles) ----------
__global__ __launch_bounds__(256) void transpose_v(const short* __restrict__ v,
                                                   short* __restrict__ vt) {
  __shared__ short t[64][72];
  const int tid = threadIdx.x;
  const int bh = blockIdx.y;
  const int sb = blockIdx.x * 64;
  const int row = tid >> 2;        // 0..63
  const int c0 = (tid & 3) * 16;   // 0,16,32,48
  const short* src = v + ((size_t)(bh * SEQ + sb + row)) * HDIM + c0;
  *(bf16x8*)&t[row][c0] = *(const bf16x8*)src;
  *(bf16x8*)&t[row][c0 + 8] = *(const bf16x8*)(src + 8);
  __syncthreads();
  bf16x8 o0, o1;
#pragma unroll
  for (int i = 0; i < 8; ++i) o0[i] = t[c0 + i][row];
#pragma unroll
  for (int i = 0; i < 8; ++i) o1[i] = t[c0 + 8 + i][row];
  short* dst = vt + ((size_t)(bh * HDIM + row)) * SEQ + sb + c0;
  *(bf16x8*)dst = o0;
  *(bf16x8*)(dst + 8) = o1;
}

// ---------- 128x128x64 NT GEMM, double-buffered prefetch ----------
#define STAGE_QKV(bb, kk0)                                                     \
  {                                                                            \
    _Pragma("unroll") for (int c = 0; c < 4; ++c) {                            \
      int oo = o + c * 1024;                                                   \
      int row = oo >> 7;                                                       \
      int scol = (oo & 127) ^ ((row & 7) << 4);                                \
      gload_lds16((const char*)A + ((size_t)(row0 + row) * K + (kk0)) * 2 + scol, \
                  (char*)As[bb] + (w * 4 + c) * 1024);                         \
      gload_lds16((const char*)Bm + ((size_t)(col0 + row) * K + (kk0)) * 2 + scol,\
                  (char*)Bs[bb] + (w * 4 + c) * 1024);                         \
    }                                                                          \
  }

__global__ __launch_bounds__(256) void gemm_qkv(
    const short* __restrict__ A, const short* __restrict__ Bm,
    const float* __restrict__ bias, short* __restrict__ qkvws) {
  __shared__ short As[2][128 * 64];
  __shared__ short Bs[2][128 * 64];
  const int tid = threadIdx.x;
  const int w = tid >> 6, l = tid & 63;
  const int l15 = l & 15, l4 = l >> 4;
  const int wr = w >> 1, wc = w & 1;
  const int row0 = blockIdx.x * 128;
  const int col0 = blockIdx.y * 128;
  const int K = EMB;

  f32x4 acc[4][4] = {};

  const int o = (w * 4) * 1024 + l * 16;
  STAGE_QKV(0, 0);
  __syncthreads();

  int cur = 0;
  for (int k0 = 0; k0 < K; k0 += 64) {
    if (k0 + 64 < K) STAGE_QKV(cur ^ 1, k0 + 64);
#pragma unroll
    for (int kk = 0; kk < 2; ++kk) {
      bf16x8 af[4], bfr[4];
      const int kb = (kk * 64 + l4 * 16) ^ ((l15 & 7) << 4);
#pragma unroll
      for (int i = 0; i < 4; ++i) {
        af[i] = *(const bf16x8*)((const char*)As[cur] + (wr * 64 + i * 16 + l15) * 128 + kb);
        bfr[i] = *(const bf16x8*)((const char*)Bs[cur] + (wc * 64 + i * 16 + l15) * 128 + kb);
      }
#pragma unroll
      for (int i = 0; i < 4; ++i)
#pragma unroll
        for (int j = 0; j < 4; ++j)
          acc[i][j] = __builtin_amdgcn_mfma_f32_16x16x32_bf16(af[i], bfr[j], acc[i][j], 0, 0, 0);
    }
    __syncthreads();
    cur ^= 1;
  }

#pragma unroll
  for (int j = 0; j < 4; ++j) {
    int f = col0 + wc * 64 + j * 16 + l15;
    float bv = bias[f];
    int part = f >> 10;               // 0=Q 1=K 2=V
    int e = f & 1023;
    int hh = e >> 6, d = e & 63;
#pragma unroll
    for (int i = 0; i < 4; ++i) {
#pragma unroll
      for (int rr = 0; rr < 4; ++rr) {
        int m = row0 + wr * 64 + i * 16 + l4 * 4 + rr;
        int bb = m >> 10, ss = m & 1023;
        qkvws[(size_t)part * 4194304 +
              ((size_t)(bb * NH + hh) * SEQ + ss) * HDIM + d] =
            f2bf(acc[i][j][rr] + bv);
      }
    }
  }
}

// ---------- 128x64x64 NT GEMM for out-proj, double-buffered prefetch ----------
#define STAGE_OUT(bb, kk0)                                                     \
  {                                                                            \
    _Pragma("unroll") for (int c = 0; c < 4; ++c) {                            \
      int oo = oA + c * 1024;                                                  \
      int row = oo >> 7;                                                       \
      int scol = (oo & 127) ^ ((row & 7) << 4);                                \
      gload_lds16((const char*)A + ((size_t)(row0 + row) * K + (kk0)) * 2 + scol, \
                  (char*)As[bb] + (w * 4 + c) * 1024);                         \
    }                                                                          \
    _Pragma("unroll") for (int c = 0; c < 2; ++c) {                            \
      int oo = oB + c * 1024;                                                  \
      int row = oo >> 7;                                                       \
      int scol = (oo & 127) ^ ((row & 7) << 4);                                \
      gload_lds16((const char*)Bm + ((size_t)(col0 + row) * K + (kk0)) * 2 + scol,\
                  (char*)Bs[bb] + (w * 2 + c) * 1024);                         \
    }                                                                          \
  }

__global__ __launch_bounds__(256) void gemm_out64(
    const short* __restrict__ A, const short* __restrict__ Bm,
    const float* __restrict__ bias, float* __restrict__ outp) {
  __shared__ short As[2][128 * 64];
  __shared__ short Bs[2][64 * 64];
  const int tid = threadIdx.x;
  const int w = tid >> 6, l = tid & 63;
  const int l15 = l & 15, l4 = l >> 4;
  const int row0 = blockIdx.x * 128;
  const int col0 = blockIdx.y * 64;
  const int K = EMB;

  f32x4 acc[2][4] = {};

  const int oA = (w * 4) * 1024 + l * 16;
  const int oB = (w * 2) * 1024 + l * 16;
  STAGE_OUT(0, 0);
  __syncthreads();

  int cur = 0;
  for (int k0 = 0; k0 < K; k0 += 64) {
    if (k0 + 64 < K) STAGE_OUT(cur ^ 1, k0 + 64);
#pragma unroll
    for (int kk = 0; kk < 2; ++kk) {
      bf16x8 af[2], bfr[4];
      const int kb = (kk * 64 + l4 * 16) ^ ((l15 & 7) << 4);
#pragma unroll
      for (int i = 0; i < 2; ++i)
        af[i] = *(const bf16x8*)((const char*)As[cur] + (w * 32 + i * 16 + l15) * 128 + kb);
#pragma unroll
      for (int j = 0; j < 4; ++j)
        bfr[j] = *(const bf16x8*)((const char*)Bs[cur] + (j * 16 + l15) * 128 + kb);
#pragma unroll
      for (int i = 0; i < 2; ++i)
#pragma unroll
        for (int j = 0; j < 4; ++j)
          acc[i][j] = __builtin_amdgcn_mfma_f32_16x16x32_bf16(af[i], bfr[j], acc[i][j], 0, 0, 0);
    }
    __syncthreads();
    cur ^= 1;
  }

#pragma unroll
  for (int j = 0; j < 4; ++j) {
    int f = col0 + j * 16 + l15;
    float bv = bias[f];
#pragma unroll
    for (int i = 0; i < 2; ++i)
#pragma unroll
      for (int rr = 0; rr < 4; ++rr) {
        int m = row0 + w * 32 + i * 16 + l4 * 4 + rr;
        __builtin_nontemporal_store(acc[i][j][rr] + bv, &outp[(size_t)m * EMB + f]);
      }
  }
}

// ---------- fused attention per (b,h, 32-row block); 2 blocks/CU ----------
__global__ __launch_bounds__(256) void attn_kernel(
    const short* __restrict__ qws, const short* __restrict__ kws,
    const short* __restrict__ vtws, float* __restrict__ attg,
    short* __restrict__ aow) {
  __shared__ short strip[32 * SPAD];  // unnormalized exp(scores), bf16 (66 KB)
  __shared__ float wsum[4][32];
  __shared__ float inv_sum[32];

  const int tid = threadIdx.x;
  const int w = tid >> 6, l = tid & 63;
  const int l15 = l & 15, l4 = l >> 4;
  const int blk = blockIdx.x;
  const int bh = blk >> 5;       // 0..63
  const int r = blk & 31;        // 32-row block index
  const int rowbase = r * 32;

  const short* qb = qws + ((size_t)bh * SEQ + rowbase) * HDIM;
  const short* kb = kws + (size_t)bh * SEQ * HDIM;
  const short* vb = vtws + (size_t)bh * HDIM * SEQ;

  bf16x8 qf[2][2];
#pragma unroll
  for (int rg = 0; rg < 2; ++rg)
#pragma unroll
    for (int ks = 0; ks < 2; ++ks)
      qf[rg][ks] = *(const bf16x8*)(qb + (rg * 16 + l15) * HDIM + ks * 32 + l4 * 8);

  const int ngroups = (rowbase + 32) >> 4;  // 2r+2 groups of 16 cols (even)
  float psum[2][4] = {};

  for (int g = w; g < ngroups; g += 4) {
    const short* kg = kb + (g * 16 + l15) * HDIM + l4 * 8;
    bf16x8 kf0 = *(const bf16x8*)(kg);
    bf16x8 kf1 = *(const bf16x8*)(kg + 32);
    f32x4 a0 = {}, a1 = {};
    a0 = __builtin_amdgcn_mfma_f32_16x16x32_bf16(qf[0][0], kf0, a0, 0, 0, 0);
    a0 = __builtin_amdgcn_mfma_f32_16x16x32_bf16(qf[0][1], kf1, a0, 0, 0, 0);
    a1 = __builtin_amdgcn_mfma_f32_16x16x32_bf16(qf[1][0], kf0, a1, 0, 0, 0);
    a1 = __builtin_amdgcn_mfma_f32_16x16x32_bf16(qf[1][1], kf1, a1, 0, 0, 0);
    int col = g * 16 + l15;
#pragma unroll
    for (int rg = 0; rg < 2; ++rg) {
#pragma unroll
      for (int rr = 0; rr < 4; ++rr) {
        int rloc = rg * 16 + l4 * 4 + rr;
        int row = rowbase + rloc;
        float sv = (rg ? a1[rr] : a0[rr]) * 0.125f;
        float ev = (col <= row) ? __expf(sv) : 0.0f;
        psum[rg][rr] += ev;
        strip[rloc * SPAD + col] = f2bf(ev);
      }
    }
  }

#pragma unroll
  for (int rg = 0; rg < 2; ++rg)
#pragma unroll
    for (int rr = 0; rr < 4; ++rr) {
      float v = psum[rg][rr];
      v += __shfl_xor(v, 1);
      v += __shfl_xor(v, 2);
      v += __shfl_xor(v, 4);
      v += __shfl_xor(v, 8);
      psum[rg][rr] = v;
    }
  if (l15 == 0) {
#pragma unroll
    for (int rg = 0; rg < 2; ++rg)
#pragma unroll
      for (int rr = 0; rr < 4; ++rr)
        wsum[w][rg * 16 + l4 * 4 + rr] = psum[rg][rr];
  }
  __syncthreads();
  if (tid < 32) {
    float s = wsum[0][tid] + wsum[1][tid] + wsum[2][tid] + wsum[3][tid];
    inv_sum[tid] = 1.0f / s;
  }
  __syncthreads();

  // write normalized att (full 1024 cols; zeros beyond causal limit), NT stores
  {
    const int limit = ngroups * 16;
    const int rloc = tid >> 3;
    const int cb = tid & 7;
    float* arow = attg + (size_t)bh * SEQ * SEQ + (size_t)(rowbase + rloc) * SEQ;
    float isr = inv_sum[rloc];
#pragma unroll
    for (int i = 0; i < 16; ++i) {
      int c = (cb + i * 8) * 8;
      f32x4 o0, o1;
      if (c < limit) {
        bf16x8 p = *(const bf16x8*)&strip[rloc * SPAD + c];
        o0[0] = bf2f(p[0]) * isr; o0[1] = bf2f(p[1]) * isr;
        o0[2] = bf2f(p[2]) * isr; o0[3] = bf2f(p[3]) * isr;
        o1[0] = bf2f(p[4]) * isr; o1[1] = bf2f(p[5]) * isr;
        o1[2] = bf2f(p[6]) * isr; o1[3] = bf2f(p[7]) * isr;
      } else {
        o0 = (f32x4)0.0f;
        o1 = (f32x4)0.0f;
      }
      __builtin_nontemporal_store(o0, (f32x4*)(arow + c));
      __builtin_nontemporal_store(o1, (f32x4*)(arow + c + 4));
    }
  }

  // PV: out[32 x 64] from strip (unnormalized) x V^T, scale rows by inv_sum
  {
    const int nch = ngroups >> 1;  // r+1 chunks of 32 keys
    const int d0 = w * 16;
    f32x4 oacc[2] = {};
    const short* vrow = vb + (d0 + l15) * SEQ + l4 * 8;
    for (int c = 0; c < nch; ++c) {
      bf16x8 vf = *(const bf16x8*)(vrow + c * 32);
      bf16x8 p0 = *(const bf16x8*)&strip[(0 + l15) * SPAD + c * 32 + l4 * 8];
      bf16x8 p1 = *(const bf16x8*)&strip[(16 + l15) * SPAD + c * 32 + l4 * 8];
      oacc[0] = __builtin_amdgcn_mfma_f32_16x16x32_bf16(p0, vf, oacc[0], 0, 0, 0);
      oacc[1] = __builtin_amdgcn_mfma_f32_16x16x32_bf16(p1, vf, oacc[1], 0, 0, 0);
    }
    const int b = bh >> 4, h = bh & 15;
#pragma unroll
    for (int rg = 0; rg < 2; ++rg) {
#pragma unroll
      for (int rr = 0; rr < 4; ++rr) {
        int rloc = rg * 16 + l4 * 4 + rr;
        int s = rowbase + rloc;
        float v = oacc[rg][rr] * inv_sum[rloc];
        aow[((size_t)(b * SEQ + s)) * EMB + h * HDIM + d0 + l15] = f2bf(v);
      }
    }
  }
}

extern "C" void kernel_launch(void* const* d_in, const int* in_sizes, int n_in,
                              void* d_out, int out_size, void* d_ws, size_t ws_size,
                              hipStream_t stream) {
  (void)in_sizes; (void)n_in; (void)out_size; (void)ws_size;
  const float* x = (const float*)d_in[0];
  const float* ipw = (const float*)d_in[2];
  const float* ipb = (const float*)d_in[3];
  const float* ow = (const float*)d_in[4];
  const float* ob = (const float*)d_in[5];
  float* outp = (float*)d_out;
  float* attg = (float*)d_out + (size_t)BATCH * SEQ * EMB;

  char* ws = (char*)d_ws;
  short* xbf = (short*)(ws);                   //  8,388,608 B (dead after QKV gemm)
  short* wbf = (short*)(ws + 8388608);         //  6,291,456 B
  short* owbf = (short*)(ws + 14680064);       //  2,097,152 B
  short* qkvws = (short*)(ws + 16777216);      // 25,165,824 B  (Q | K | V, [bh][s][d])
  short* aow = (short*)(ws + 41943040);        //  8,388,608 B -> 50,331,648 total
  short* vtws = (short*)(ws);                  // aliases xbf (dead by transpose time)

  short* qws = qkvws;
  short* kws = qkvws + 4194304;
  short* vws = qkvws + 8388608;

  cvt3_kernel<<<4096, 256, 0, stream>>>(x, ipw, ow, xbf, wbf, owbf);

  dim3 g1(32, 24);
  gemm_qkv<<<g1, 256, 0, stream>>>(xbf, wbf, ipb, qkvws);

  transpose_v<<<dim3(16, 64), 256, 0, stream>>>(vws, vtws);

  attn_kernel<<<2048, 256, 0, stream>>>(qws, kws, vtws, attg, aow);

  gemm_out64<<<dim3(32, 16), 256, 0, stream>>>(aow, owbf, ob, outp);
}